// Round 1
// baseline (29292.377 us; speedup 1.0000x reference)
//
#include <hip/hip_runtime.h>
#include <cstdint>
#include <cstddef>

#define T_LEN 512
#define S_LEN 512
#define HID   1024
#define AD    256
#define VOC   50257
#define G3    3072
#define NWG   128
#define NPART (197*4)

// ---------------- workspace layout (float offsets) ----------------
#define WS_GENC   0
#define WS_GITOK  (WS_GENC + G3*S_LEN)          // [512][3072]
#define WS_EX     (WS_GITOK + T_LEN*G3)         // [512][256]
#define WS_H1     (WS_EX + S_LEN*AD)            // [512][1024]
#define WS_FC1    (WS_H1 + T_LEN*HID)           // [512][32]
#define WS_NH0    (WS_FC1 + T_LEN*32)
#define WS_NH1    (WS_NH0 + HID)
#define WS_GH0    (WS_NH1 + HID)
#define WS_GH1    (WS_GH0 + G3)
#define WS_W      (WS_GH1 + G3)
#define WS_U0     (WS_W + S_LEN)
#define WS_U1     (WS_U0 + AD)
#define WS_E0P    (WS_U1 + AD)
#define WS_E1P    (WS_E0P + 32)
#define WS_BAR    (WS_E1P + 16)                  // 64 uint slots
#define WS_ROWP   (WS_BAR + 64)                  // [512][788]
#define WS_INV    (WS_ROWP + T_LEN*NPART)
#define WS_END    (WS_INV + T_LEN)

__device__ inline float wred64(float v) {
  v += __shfl_xor(v, 32, 64); v += __shfl_xor(v, 16, 64); v += __shfl_xor(v, 8, 64);
  v += __shfl_xor(v, 4, 64);  v += __shfl_xor(v, 2, 64);  v += __shfl_xor(v, 1, 64);
  return v;
}

__device__ inline float fast_sigmoid(float x) { return 1.f / (1.f + __expf(-x)); }
__device__ inline float fast_tanh(float x) {
  float e = __expf(2.f * x);
  return 1.f - 2.f / (e + 1.f);
}

// device-scope grid barrier (sense via generation counter)
__device__ inline void gbar(unsigned* bar, unsigned nwg) {
  __syncthreads();
  if (threadIdx.x == 0) {
    unsigned* cnt = bar;
    unsigned* gen = bar + 32;
    __threadfence();  // release my WG's stage writes device-wide
    unsigned g = __hip_atomic_load(gen, __ATOMIC_RELAXED, __HIP_MEMORY_SCOPE_AGENT);
    unsigned old = __hip_atomic_fetch_add(cnt, 1u, __ATOMIC_ACQ_REL, __HIP_MEMORY_SCOPE_AGENT);
    if (old == nwg - 1u) {
      __hip_atomic_store(cnt, 0u, __ATOMIC_RELAXED, __HIP_MEMORY_SCOPE_AGENT);
      __hip_atomic_store(gen, g + 1u, __ATOMIC_RELEASE, __HIP_MEMORY_SCOPE_AGENT);
    } else {
      while (__hip_atomic_load(gen, __ATOMIC_RELAXED, __HIP_MEMORY_SCOPE_AGENT) == g) {
        __builtin_amdgcn_s_sleep(1);
      }
    }
    __threadfence();  // acquire: invalidate caches so fresh data is visible
  }
  __syncthreads();
}

// ---------------- init: zero recurrent state, gh1 = bhh1, barrier = 0 ----------------
__global__ void k_init(float* ws, const float* __restrict__ bhh1) {
  const int tid = threadIdx.x;
  for (int i = tid; i < HID; i += 256) { ws[WS_NH0 + i] = 0.f; ws[WS_NH1 + i] = 0.f; }
  for (int i = tid; i < AD;  i += 256) { ws[WS_U0 + i] = 0.f;  ws[WS_U1 + i] = 0.f; }
  if (tid < 32) ws[WS_E0P + tid] = 0.f;
  if (tid < 16) ws[WS_E1P + tid] = 0.f;
  for (int i = tid; i < G3; i += 256) ws[WS_GH1 + i] = bhh1[i];
  if (tid < 64) ((unsigned*)(ws + WS_BAR))[tid] = 0u;
}

// ---------------- generic tiled fp32 GEMM: C[M,N] = act(A[g(m),:1024] . B[n, kofs:kofs+1024] + bias[n]) ----------------
__global__ __launch_bounds__(256) void k_gemm(
    const float* __restrict__ A, int lda, const int* __restrict__ gidx,
    const float* __restrict__ B, int ldb, int kofs,
    const float* __restrict__ bias, float* __restrict__ C, int ldc,
    int M, int N, int act)
{
  __shared__ float As[64][33];
  __shared__ float Bs[64][33];
  const int bm = blockIdx.y * 64, bn = blockIdx.x * 64;
  const int tx = threadIdx.x & 15, ty = threadIdx.x >> 4;
  float acc[4][4] = {};
  const int lin = threadIdx.x * 8;
  const int lr = lin >> 5;   // 0..63
  const int lc = lin & 31;   // 0,8,16,24
  for (int k0 = 0; k0 < 1024; k0 += 32) {
    {
      const int gm = bm + lr;
      float4 v0 = {0,0,0,0}, v1 = {0,0,0,0};
      if (gm < M) {
        const int row = gidx ? gidx[gm] : gm;
        const float* p = A + (size_t)row * lda + k0 + lc;
        v0 = *(const float4*)p; v1 = *(const float4*)(p + 4);
      }
      As[lr][lc+0]=v0.x; As[lr][lc+1]=v0.y; As[lr][lc+2]=v0.z; As[lr][lc+3]=v0.w;
      As[lr][lc+4]=v1.x; As[lr][lc+5]=v1.y; As[lr][lc+6]=v1.z; As[lr][lc+7]=v1.w;
    }
    {
      const int gn = bn + lr;
      float4 v0 = {0,0,0,0}, v1 = {0,0,0,0};
      if (gn < N) {
        const float* p = B + (size_t)gn * ldb + kofs + k0 + lc;
        v0 = *(const float4*)p; v1 = *(const float4*)(p + 4);
      }
      Bs[lr][lc+0]=v0.x; Bs[lr][lc+1]=v0.y; Bs[lr][lc+2]=v0.z; Bs[lr][lc+3]=v0.w;
      Bs[lr][lc+4]=v1.x; Bs[lr][lc+5]=v1.y; Bs[lr][lc+6]=v1.z; Bs[lr][lc+7]=v1.w;
    }
    __syncthreads();
    #pragma unroll
    for (int kk = 0; kk < 32; ++kk) {
      float a0 = As[ty*4+0][kk], a1 = As[ty*4+1][kk], a2 = As[ty*4+2][kk], a3 = As[ty*4+3][kk];
      float b0 = Bs[tx*4+0][kk], b1 = Bs[tx*4+1][kk], b2 = Bs[tx*4+2][kk], b3 = Bs[tx*4+3][kk];
      acc[0][0]=fmaf(a0,b0,acc[0][0]); acc[0][1]=fmaf(a0,b1,acc[0][1]); acc[0][2]=fmaf(a0,b2,acc[0][2]); acc[0][3]=fmaf(a0,b3,acc[0][3]);
      acc[1][0]=fmaf(a1,b0,acc[1][0]); acc[1][1]=fmaf(a1,b1,acc[1][1]); acc[1][2]=fmaf(a1,b2,acc[1][2]); acc[1][3]=fmaf(a1,b3,acc[1][3]);
      acc[2][0]=fmaf(a2,b0,acc[2][0]); acc[2][1]=fmaf(a2,b1,acc[2][1]); acc[2][2]=fmaf(a2,b2,acc[2][2]); acc[2][3]=fmaf(a2,b3,acc[2][3]);
      acc[3][0]=fmaf(a3,b0,acc[3][0]); acc[3][1]=fmaf(a3,b1,acc[3][1]); acc[3][2]=fmaf(a3,b2,acc[3][2]); acc[3][3]=fmaf(a3,b3,acc[3][3]);
    }
    __syncthreads();
  }
  #pragma unroll
  for (int i = 0; i < 4; ++i)
    #pragma unroll
    for (int j = 0; j < 4; ++j) {
      const int m = bm + ty*4 + i, n = bn + tx*4 + j;
      if (m < M && n < N) {
        float v = acc[i][j] + (bias ? bias[n] : 0.f);
        if (act == 1) v = fmaxf(v, 0.f);
        C[(size_t)m * ldc + n] = v;
      }
    }
}

// 1024-dot: wave covers the row; returns full sum on all lanes
__device__ inline float dot1024(const float* __restrict__ Wrow, const float* xv, int lane) {
  const float4* W4 = (const float4*)Wrow;
  const float4* X4 = (const float4*)xv;
  float acc = 0.f;
  #pragma unroll
  for (int p = 0; p < 4; ++p) {
    float4 w = W4[p*64 + lane];
    float4 x = X4[p*64 + lane];
    acc = fmaf(w.x, x.x, acc); acc = fmaf(w.y, x.y, acc);
    acc = fmaf(w.z, x.z, acc); acc = fmaf(w.w, x.w, acc);
  }
  return wred64(acc);
}

// ---------------- persistent recurrence kernel: 128 WGs, 4 grid barriers / step ----------------
__global__ __launch_bounds__(256) void k_recur(
    float* __restrict__ ws,
    const float* __restrict__ Whh0, const float* __restrict__ bhh0,
    const float* __restrict__ Wih1, const float* __restrict__ bih1,
    const float* __restrict__ Whh1, const float* __restrict__ bhh1,
    const float* __restrict__ Wh,   const float* __restrict__ bh,
    const float* __restrict__ vh,   const float* __restrict__ vhb,
    const float* __restrict__ va,   const float* __restrict__ vab,
    const float* __restrict__ Wac)
{
  float* Genc  = ws + WS_GENC;
  float* gitok = ws + WS_GITOK;
  float* Ex    = ws + WS_EX;
  float* H1    = ws + WS_H1;
  float* nh0   = ws + WS_NH0;
  float* nh1   = ws + WS_NH1;
  float* gh0b  = ws + WS_GH0;
  float* gh1b  = ws + WS_GH1;
  float* wbuf  = ws + WS_W;
  float* u0    = ws + WS_U0;
  float* u1    = ws + WS_U1;
  float* e0p   = ws + WS_E0P;
  float* e1p   = ws + WS_E1P;
  unsigned* bar = (unsigned*)(ws + WS_BAR);

  const int wg = blockIdx.x, tid = threadIdx.x;
  const int lane = tid & 63, wv = tid >> 6;

  __shared__ float xv[HID];
  __shared__ float exb[16 * AD];   // w-role: persistent Ex slice (16 KB)
  __shared__ float wl[S_LEN];
  __shared__ float cb[AD];
  __shared__ float vas[AD];
  __shared__ float sal[2];
  __shared__ float sred[4];
  __shared__ float sinv[1];

  const bool wrole = (wg >= 96);
  if (wrole) {
    const int s0 = (wg - 96) * 16;
    for (int i = tid; i < 16 * AD; i += 256) exb[i] = Ex[s0 * AD + i];
  }
  vas[tid] = va[tid];
  const float vabv = vab[0];
  const float vhb0 = vhb[0];

  #pragma unroll 1
  for (int t = 0; t < T_LEN; ++t) {
    // ---------- S1: alpha; gh0 = Whh0 @ h0n + bhh0 ; attention weights w ----------
    if (tid == 0) {
      float e0 = vhb0, e1 = vhb0;
      #pragma unroll 1
      for (int i = 0; i < 32; ++i) e0 += e0p[i];
      #pragma unroll 1
      for (int i = 0; i < 16; ++i) e1 += e1p[i];
      float a0 = __expf(e0), a1 = __expf(e1);
      float s = a0 + a1;
      sal[0] = a0 / s; sal[1] = a1 / s;
    }
    __syncthreads();
    const float al0 = sal[0], al1 = sal[1];
    if (!wrole) {
      // h0n = al0*nh0_prev + al1*nh1_prev staged in LDS
      {
        float4 a = ((const float4*)nh0)[tid];
        float4 b = ((const float4*)nh1)[tid];
        float4 r;
        r.x = al0*a.x + al1*b.x; r.y = al0*a.y + al1*b.y;
        r.z = al0*a.z + al1*b.z; r.w = al0*a.w + al1*b.w;
        ((float4*)xv)[tid] = r;
      }
      __syncthreads();
      const int rbase = wg * 32 + wv * 8;
      #pragma unroll 1
      for (int rr = 0; rr < 8; ++rr) {
        const int r = rbase + rr;
        float acc = dot1024(Whh0 + (size_t)r * HID, xv, lane);
        if (lane == 0) gh0b[r] = acc + bhh0[r];
      }
    } else {
      cb[tid] = al0 * u0[tid] + al1 * u1[tid];   // c = Wa_c @ h0n (via u0,u1)
      __syncthreads();
      const int s0 = (wg - 96) * 16;
      const int sl = wv * 4 + (lane >> 4);
      const int il = lane & 15;
      float acc = 0.f;
      #pragma unroll
      for (int k = 0; k < 16; ++k) {
        const int i = il + k * 16;
        acc = fmaf(vas[i], fast_tanh(exb[sl * AD + i] + cb[i]), acc);
      }
      acc += __shfl_xor(acc, 8, 64); acc += __shfl_xor(acc, 4, 64);
      acc += __shfl_xor(acc, 2, 64); acc += __shfl_xor(acc, 1, 64);
      if (il == 0) wbuf[s0 + sl] = __expf(acc + vabv);
    }
    gbar(bar, NWG);

    // ---------- S2: gi0 = (Genc @ w)/sum(w) + gi_tok[t]; nh0 = GRU-combine ----------
    wl[tid] = wbuf[tid]; wl[tid + 256] = wbuf[tid + 256];
    __syncthreads();
    {
      float p = wl[tid] + wl[tid + 256];
      p = wred64(p);
      if (lane == 0) sred[wv] = p;
    }
    __syncthreads();
    if (tid == 0) sinv[0] = 1.f / (sred[0] + sred[1] + sred[2] + sred[3]);
    __syncthreads();
    const float inv = sinv[0];
    {
      const int j0 = wg * 8 + wv * 2;
      #pragma unroll 1
      for (int jj = 0; jj < 2; ++jj) {
        const int j = j0 + jj;
        float d[3];
        #pragma unroll 1
        for (int part = 0; part < 3; ++part) {
          const int r = part * HID + j;
          const float4* G4 = (const float4*)(Genc + (size_t)r * S_LEN);
          const float4* W4 = (const float4*)wl;
          float acc = 0.f;
          #pragma unroll
          for (int p = 0; p < 2; ++p) {
            float4 g = G4[p*64 + lane];
            float4 w = W4[p*64 + lane];
            acc = fmaf(g.x, w.x, acc); acc = fmaf(g.y, w.y, acc);
            acc = fmaf(g.z, w.z, acc); acc = fmaf(g.w, w.w, acc);
          }
          d[part] = wred64(acc);
        }
        if (lane == 0) {
          const float* git = gitok + (size_t)t * G3;
          const float gr = d[0] * inv + git[j];
          const float gz = d[1] * inv + git[HID + j];
          const float gn = d[2] * inv + git[2 * HID + j];
          const float rg = fast_sigmoid(gr + gh0b[j]);
          const float zg = fast_sigmoid(gz + gh0b[HID + j]);
          const float ng = fast_tanh(gn + rg * gh0b[2 * HID + j]);
          const float h0j = al0 * nh0[j] + al1 * nh1[j];
          nh0[j] = (1.f - zg) * ng + zg * h0j;
        }
      }
    }
    gbar(bar, NWG);

    // ---------- S3: nh1 = GRU1(nh0, h1) ; e0 partials ; u0 = Wa_c @ nh0 ----------
    ((float4*)xv)[tid] = ((const float4*)nh0)[tid];
    __syncthreads();
    if (wg < 64) {
      const int jb = wg * 16 + wv * 4;
      #pragma unroll 1
      for (int jj = 0; jj < 4; ++jj) {
        const int j = jb + jj;
        float d[3];
        #pragma unroll 1
        for (int part = 0; part < 3; ++part) {
          const int r = part * HID + j;
          d[part] = dot1024(Wih1 + (size_t)r * HID, xv, lane);
        }
        if (lane == 0) {
          const float gr = d[0] + bih1[j];
          const float gz = d[1] + bih1[HID + j];
          const float gn = d[2] + bih1[2 * HID + j];
          const float rg = fast_sigmoid(gr + gh1b[j]);
          const float zg = fast_sigmoid(gz + gh1b[HID + j]);
          const float ng = fast_tanh(gn + rg * gh1b[2 * HID + j]);
          const float v = (1.f - zg) * ng + zg * nh1[j];
          nh1[j] = v;
          H1[(size_t)t * HID + j] = v;
        }
      }
    } else if (wg < 96) {
      const int rb = (wg - 64) * 8 + wv * 2;
      float wacc = 0.f;
      #pragma unroll 1
      for (int rr = 0; rr < 2; ++rr) {
        const int r = rb + rr;
        float acc = dot1024(Wh + (size_t)r * HID, xv, lane);
        if (lane == 0) wacc += vh[r] * fast_tanh(acc + bh[r]);
      }
      if (lane == 0) sred[wv] = wacc;
      __syncthreads();
      if (tid == 0) e0p[wg - 64] = sred[0] + sred[1] + sred[2] + sred[3];
    } else {
      const int rb = (wg - 96) * 8 + wv * 2;
      #pragma unroll 1
      for (int rr = 0; rr < 2; ++rr) {
        const int r = rb + rr;
        float acc = dot1024(Wac + (size_t)r * HID, xv, lane);
        if (lane == 0) u0[r] = acc;
      }
    }
    gbar(bar, NWG);

    // ---------- S4: gh1_next = Whh1 @ nh1 + bhh1 ; e1 partials ; u1 = Wa_c @ nh1 ----------
    ((float4*)xv)[tid] = ((const float4*)nh1)[tid];
    __syncthreads();
    if (wg < 96) {
      const int rbase = wg * 32 + wv * 8;
      #pragma unroll 1
      for (int rr = 0; rr < 8; ++rr) {
        const int r = rbase + rr;
        float acc = dot1024(Whh1 + (size_t)r * HID, xv, lane);
        if (lane == 0) gh1b[r] = acc + bhh1[r];
      }
    } else if (wg < 112) {
      const int rb = (wg - 96) * 16 + wv * 4;
      float wacc = 0.f;
      #pragma unroll 1
      for (int rr = 0; rr < 4; ++rr) {
        const int r = rb + rr;
        float acc = dot1024(Wh + (size_t)r * HID, xv, lane);
        if (lane == 0) wacc += vh[r] * fast_tanh(acc + bh[r]);
      }
      if (lane == 0) sred[wv] = wacc;
      __syncthreads();
      if (tid == 0) e1p[wg - 96] = sred[0] + sred[1] + sred[2] + sred[3];
    } else {
      const int rb = (wg - 112) * 16 + wv * 4;
      #pragma unroll 1
      for (int rr = 0; rr < 4; ++rr) {
        const int r = rb + rr;
        float acc = dot1024(Wac + (size_t)r * HID, xv, lane);
        if (lane == 0) u1[r] = acc;
      }
    }
    gbar(bar, NWG);
  }
}

// ---------------- output head: logits -> exp -> per-wave row partials ----------------
__global__ __launch_bounds__(256) void k_head(
    const float* __restrict__ FC1, const float* __restrict__ Wf2,
    const float* __restrict__ bf2, float* __restrict__ out, float* __restrict__ rowp)
{
  __shared__ float fcb[256 * 32];   // 32 KB: half of the t-range
  const int v = blockIdx.x * 256 + threadIdx.x;
  const bool ok = v < VOC;
  float wf[32];
  float bb = 0.f;
  if (ok) {
    const float4* W4 = (const float4*)(Wf2 + (size_t)v * 32);
    #pragma unroll
    for (int q = 0; q < 8; ++q) ((float4*)wf)[q] = W4[q];
    bb = bf2[v];
  }
  const int wv = threadIdx.x >> 6;
  #pragma unroll 1
  for (int half = 0; half < 2; ++half) {
    __syncthreads();
    for (int i = threadIdx.x; i < 256 * 32 / 4; i += 256)
      ((float4*)fcb)[i] = ((const float4*)(FC1 + half * 256 * 32))[i];
    __syncthreads();
    #pragma unroll 1
    for (int tt = 0; tt < 256; ++tt) {
      const int t = half * 256 + tt;
      const float4* f4 = (const float4*)(fcb + tt * 32);
      float acc = bb;
      #pragma unroll
      for (int q = 0; q < 8; ++q) {
        float4 f = f4[q];
        acc = fmaf(wf[4*q+0], f.x, acc);
        acc = fmaf(wf[4*q+1], f.y, acc);
        acc = fmaf(wf[4*q+2], f.z, acc);
        acc = fmaf(wf[4*q+3], f.w, acc);
      }
      const float w = ok ? __expf(acc) : 0.f;
      if (ok) out[(size_t)t * VOC + v] = w;
      float r = wred64(w);
      if ((threadIdx.x & 63) == 0)
        rowp[(size_t)t * NPART + (size_t)blockIdx.x * 4 + wv] = r;
    }
  }
}

__global__ __launch_bounds__(256) void k_rowsum(const float* __restrict__ rowp, float* __restrict__ inv) {
  const int t = blockIdx.x;
  float acc = 0.f;
  for (int i = threadIdx.x; i < NPART; i += 256) acc += rowp[(size_t)t * NPART + i];
  acc = wred64(acc);
  __shared__ float sr[4];
  if ((threadIdx.x & 63) == 0) sr[threadIdx.x >> 6] = acc;
  __syncthreads();
  if (threadIdx.x == 0) inv[t] = 1.f / (sr[0] + sr[1] + sr[2] + sr[3]);
}

__global__ __launch_bounds__(256) void k_scale(float* __restrict__ out, const float* __restrict__ inv) {
  const int t = blockIdx.y;
  const float s = inv[t];
  const size_t base = (size_t)t * VOC;
  const int v0 = blockIdx.x * 2048 + threadIdx.x;
  #pragma unroll
  for (int k = 0; k < 8; ++k) {
    const int v = v0 + k * 256;
    if (v < VOC) out[base + v] *= s;
  }
}

extern "C" void kernel_launch(void* const* d_in, const int* in_sizes, int n_in,
                              void* d_out, int out_size, void* d_ws, size_t ws_size,
                              hipStream_t stream) {
  const int*   dec  = (const int*)  d_in[0];
  const float* enc  = (const float*)d_in[1];
  const float* emb  = (const float*)d_in[2];
  const float* Wax  = (const float*)d_in[3];
  const float* Wac  = (const float*)d_in[4];
  const float* ba   = (const float*)d_in[5];
  const float* va   = (const float*)d_in[6];
  const float* vab  = (const float*)d_in[7];
  const float* Wih0 = (const float*)d_in[8];
  const float* bih0 = (const float*)d_in[9];
  const float* Whh0 = (const float*)d_in[10];
  const float* bhh0 = (const float*)d_in[11];
  const float* Wih1 = (const float*)d_in[12];
  const float* bih1 = (const float*)d_in[13];
  const float* Whh1 = (const float*)d_in[14];
  const float* bhh1 = (const float*)d_in[15];
  const float* Wh   = (const float*)d_in[16];
  const float* bh   = (const float*)d_in[17];
  const float* vh   = (const float*)d_in[18];
  const float* vhb  = (const float*)d_in[19];
  const float* Wf1  = (const float*)d_in[20];
  const float* bf1  = (const float*)d_in[21];
  const float* Wf2  = (const float*)d_in[22];
  const float* bf2  = (const float*)d_in[23];
  float* out = (float*)d_out;
  float* ws  = (float*)d_ws;

  // init recurrent state + barrier
  k_init<<<1, 256, 0, stream>>>(ws, bhh1);

  // Genc[r][s] = Wih0[r, :1024] . enc[s]          (M=3072, N=512)
  k_gemm<<<dim3(8, 48), 256, 0, stream>>>(Wih0, 2048, nullptr, enc, 1024, 0,
                                          nullptr, ws + WS_GENC, 512, G3, S_LEN, 0);
  // gi_tok[t][r] = emb[dec[t]] . Wih0[r, 1024:] + bih0[r]   (M=512, N=3072)
  k_gemm<<<dim3(48, 8), 256, 0, stream>>>(emb, 1024, dec, Wih0, 2048, 1024,
                                          bih0, ws + WS_GITOK, G3, T_LEN, G3, 0);
  // Ex[s][i] = enc[s] . Wa_x[i] + ba[i]           (M=512, N=256)
  k_gemm<<<dim3(4, 8), 256, 0, stream>>>(enc, 1024, nullptr, Wax, 1024, 0,
                                         ba, ws + WS_EX, AD, S_LEN, AD, 0);

  // sequential recurrence (persistent kernel)
  k_recur<<<NWG, 256, 0, stream>>>(ws, Whh0, bhh0, Wih1, bih1, Whh1, bhh1,
                                   Wh, bh, vh, vhb, va, vab, Wac);

  // FC1[t] = relu(Wf1 @ H1[t] + bf1)              (M=512, N=32)
  k_gemm<<<dim3(1, 8), 256, 0, stream>>>(ws + WS_H1, 1024, nullptr, Wf1, 1024, 0,
                                         bf1, ws + WS_FC1, 32, T_LEN, 32, 1);

  // logits -> exp -> partial row sums -> normalize
  k_head<<<197, 256, 0, stream>>>(ws + WS_FC1, Wf2, bf2, out, ws + WS_ROWP);
  k_rowsum<<<512, 256, 0, stream>>>(ws + WS_ROWP, ws + WS_INV);
  k_scale<<<dim3(25, 512), 256, 0, stream>>>(out, ws + WS_INV);
}

// Round 2
// 14859.225 us; speedup vs baseline: 1.9713x; 1.9713x over previous
//
#include <hip/hip_runtime.h>
#include <cstdint>
#include <cstddef>

#define T_LEN 512
#define S_LEN 512
#define HID   1024
#define AD    256
#define VOC   50257
#define G3    3072
#define NWG   128
#define NT    512
#define NPART (197*4)

// ---------------- workspace layout (float offsets) ----------------
#define WS_GENC   0
#define WS_GITOK  (WS_GENC + G3*S_LEN)          // [512][3072]
#define WS_EX     (WS_GITOK + T_LEN*G3)         // [512][256]
#define WS_H1     (WS_EX + S_LEN*AD)            // [512][1024]
#define WS_FC1    (WS_H1 + T_LEN*HID)           // [512][32]
#define WS_NH0    (WS_FC1 + T_LEN*32)
#define WS_NH1    (WS_NH0 + HID)
#define WS_GH0    (WS_NH1 + HID)
#define WS_GH1    (WS_GH0 + G3)
#define WS_W      (WS_GH1 + G3)
#define WS_U0     (WS_W + S_LEN)
#define WS_U1     (WS_U0 + AD)
#define WS_E0P    (WS_U1 + AD)
#define WS_E1P    (WS_E0P + 32)
#define WS_BAR    (WS_E1P + 16)                  // 512 uint slots (tree barrier)
#define WS_ROWP   (WS_BAR + 512)                 // [512][788]
#define WS_INV    (WS_ROWP + T_LEN*NPART)
#define WS_END    (WS_INV + T_LEN)

__device__ inline float wred64(float v) {
  v += __shfl_xor(v, 32, 64); v += __shfl_xor(v, 16, 64); v += __shfl_xor(v, 8, 64);
  v += __shfl_xor(v, 4, 64);  v += __shfl_xor(v, 2, 64);  v += __shfl_xor(v, 1, 64);
  return v;
}

__device__ inline float fast_sigmoid(float x) { return 1.f / (1.f + __expf(-x)); }
__device__ inline float fast_tanh(float x) {
  float e = __expf(2.f * x);
  return 1.f - 2.f / (e + 1.f);
}

// coherent (agent-scope, cache-bypassing) state accessors — no fences needed
__device__ inline float ldw(const float* p) {
  return __uint_as_float(__hip_atomic_load((const unsigned int*)p,
                                           __ATOMIC_RELAXED, __HIP_MEMORY_SCOPE_AGENT));
}
__device__ inline void stw(float* p, float v) {
  __hip_atomic_store((unsigned int*)p, __float_as_uint(v),
                     __ATOMIC_RELAXED, __HIP_MEMORY_SCOPE_AGENT);
}

// 2-level tree barrier: 8 leaf counters (16 WGs each) + root. Monotonic counts,
// generation tracked locally by caller (b = 1,2,3,...). No fences, no invalidation:
// data visibility is via agent-scope atomics on the state arrays themselves.
__device__ inline void gbar2(unsigned* bar, int wg, unsigned b) {
  __syncthreads();   // drains each wave's vmcnt (incl. agent-scope stores) before arrival
  if (threadIdx.x == 0) {
    unsigned* leaf = bar + (wg & 7) * 32;
    unsigned* root = bar + 256;
    unsigned* gen  = bar + 288;
    unsigned lo = __hip_atomic_fetch_add(leaf, 1u, __ATOMIC_RELAXED, __HIP_MEMORY_SCOPE_AGENT);
    if (lo == b * 16u - 1u) {
      unsigned ro = __hip_atomic_fetch_add(root, 1u, __ATOMIC_RELAXED, __HIP_MEMORY_SCOPE_AGENT);
      if (ro == b * 8u - 1u)
        __hip_atomic_store(gen, b, __ATOMIC_RELAXED, __HIP_MEMORY_SCOPE_AGENT);
    }
    while (__hip_atomic_load(gen, __ATOMIC_RELAXED, __HIP_MEMORY_SCOPE_AGENT) < b)
      __builtin_amdgcn_s_sleep(1);
  }
  __syncthreads();
}

// ---------------- init: zero recurrent state, gh1 = bhh1, barrier = 0 ----------------
__global__ void k_init(float* ws, const float* __restrict__ bhh1) {
  const int tid = threadIdx.x;
  for (int i = tid; i < HID; i += 256) { ws[WS_NH0 + i] = 0.f; ws[WS_NH1 + i] = 0.f; }
  for (int i = tid; i < AD;  i += 256) { ws[WS_U0 + i] = 0.f;  ws[WS_U1 + i] = 0.f; }
  if (tid < 32) ws[WS_E0P + tid] = 0.f;
  if (tid < 16) ws[WS_E1P + tid] = 0.f;
  for (int i = tid; i < G3; i += 256) ws[WS_GH1 + i] = bhh1[i];
  for (int i = tid; i < 512; i += 256) ((unsigned*)(ws + WS_BAR))[i] = 0u;
}

// ---------------- generic tiled fp32 GEMM (pre/post passes) ----------------
__global__ __launch_bounds__(256) void k_gemm(
    const float* __restrict__ A, int lda, const int* __restrict__ gidx,
    const float* __restrict__ B, int ldb, int kofs,
    const float* __restrict__ bias, float* __restrict__ C, int ldc,
    int M, int N, int act)
{
  __shared__ float As[64][33];
  __shared__ float Bs[64][33];
  const int bm = blockIdx.y * 64, bn = blockIdx.x * 64;
  const int tx = threadIdx.x & 15, ty = threadIdx.x >> 4;
  float acc[4][4] = {};
  const int lin = threadIdx.x * 8;
  const int lr = lin >> 5;
  const int lc = lin & 31;
  for (int k0 = 0; k0 < 1024; k0 += 32) {
    {
      const int gm = bm + lr;
      float4 v0 = {0,0,0,0}, v1 = {0,0,0,0};
      if (gm < M) {
        const int row = gidx ? gidx[gm] : gm;
        const float* p = A + (size_t)row * lda + k0 + lc;
        v0 = *(const float4*)p; v1 = *(const float4*)(p + 4);
      }
      As[lr][lc+0]=v0.x; As[lr][lc+1]=v0.y; As[lr][lc+2]=v0.z; As[lr][lc+3]=v0.w;
      As[lr][lc+4]=v1.x; As[lr][lc+5]=v1.y; As[lr][lc+6]=v1.z; As[lr][lc+7]=v1.w;
    }
    {
      const int gn = bn + lr;
      float4 v0 = {0,0,0,0}, v1 = {0,0,0,0};
      if (gn < N) {
        const float* p = B + (size_t)gn * ldb + kofs + k0 + lc;
        v0 = *(const float4*)p; v1 = *(const float4*)(p + 4);
      }
      Bs[lr][lc+0]=v0.x; Bs[lr][lc+1]=v0.y; Bs[lr][lc+2]=v0.z; Bs[lr][lc+3]=v0.w;
      Bs[lr][lc+4]=v1.x; Bs[lr][lc+5]=v1.y; Bs[lr][lc+6]=v1.z; Bs[lr][lc+7]=v1.w;
    }
    __syncthreads();
    #pragma unroll
    for (int kk = 0; kk < 32; ++kk) {
      float a0 = As[ty*4+0][kk], a1 = As[ty*4+1][kk], a2 = As[ty*4+2][kk], a3 = As[ty*4+3][kk];
      float b0 = Bs[tx*4+0][kk], b1 = Bs[tx*4+1][kk], b2 = Bs[tx*4+2][kk], b3 = Bs[tx*4+3][kk];
      acc[0][0]=fmaf(a0,b0,acc[0][0]); acc[0][1]=fmaf(a0,b1,acc[0][1]); acc[0][2]=fmaf(a0,b2,acc[0][2]); acc[0][3]=fmaf(a0,b3,acc[0][3]);
      acc[1][0]=fmaf(a1,b0,acc[1][0]); acc[1][1]=fmaf(a1,b1,acc[1][1]); acc[1][2]=fmaf(a1,b2,acc[1][2]); acc[1][3]=fmaf(a1,b3,acc[1][3]);
      acc[2][0]=fmaf(a2,b0,acc[2][0]); acc[2][1]=fmaf(a2,b1,acc[2][1]); acc[2][2]=fmaf(a2,b2,acc[2][2]); acc[2][3]=fmaf(a2,b3,acc[2][3]);
      acc[3][0]=fmaf(a3,b0,acc[3][0]); acc[3][1]=fmaf(a3,b1,acc[3][1]); acc[3][2]=fmaf(a3,b2,acc[3][2]); acc[3][3]=fmaf(a3,b3,acc[3][3]);
    }
    __syncthreads();
  }
  #pragma unroll
  for (int i = 0; i < 4; ++i)
    #pragma unroll
    for (int j = 0; j < 4; ++j) {
      const int m = bm + ty*4 + i, n = bn + tx*4 + j;
      if (m < M && n < N) {
        float v = acc[i][j] + (bias ? bias[n] : 0.f);
        if (act == 1) v = fmaxf(v, 0.f);
        C[(size_t)m * ldc + n] = v;
      }
    }
}

// ---------------- persistent recurrence kernel: 128 WGs x 512 thr, 4 tree barriers / step ----------------
__global__ __launch_bounds__(NT) void k_recur(
    float* __restrict__ ws,
    const float* __restrict__ Whh0, const float* __restrict__ bhh0,
    const float* __restrict__ Wih1, const float* __restrict__ bih1,
    const float* __restrict__ Whh1, const float* __restrict__ bhh1,
    const float* __restrict__ Wh,   const float* __restrict__ bh,
    const float* __restrict__ vh,   const float* __restrict__ vhb,
    const float* __restrict__ va,   const float* __restrict__ vab,
    const float* __restrict__ Wac)
{
  float* Genc  = ws + WS_GENC;
  float* gitok = ws + WS_GITOK;
  float* Ex    = ws + WS_EX;
  float* H1    = ws + WS_H1;
  float* nh0   = ws + WS_NH0;
  float* nh1   = ws + WS_NH1;
  float* gh0b  = ws + WS_GH0;
  float* gh1b  = ws + WS_GH1;
  float* wbuf  = ws + WS_W;
  float* u0    = ws + WS_U0;
  float* u1    = ws + WS_U1;
  float* e0p   = ws + WS_E0P;
  float* e1p   = ws + WS_E1P;
  unsigned* bar = (unsigned*)(ws + WS_BAR);

  const int wg = blockIdx.x, tid = threadIdx.x;
  const int lane = tid & 63, wv = tid >> 6;

  __shared__ float xv[HID];        // 4 KB  (h0n / nh0 / nh1 staging)
  __shared__ float exb[16 * AD];   // 16 KB (w-role: persistent Ex slice)
  __shared__ float wl[S_LEN];      // 2 KB
  __shared__ float cb[AD];
  __shared__ float vas[AD];
  __shared__ float sal[2];
  __shared__ float sred[8];
  __shared__ float sinv[1];

  const bool wrole = (wg >= 96);
  if (wrole) {
    const int s0 = (wg - 96) * 16;
    for (int i = tid; i < 16 * AD; i += NT) exb[i] = Ex[(size_t)s0 * AD + i];
  }
  if (tid < AD) vas[tid] = va[tid];
  const float vabv = vab[0];
  const float vhb0 = vhb[0];
  unsigned bcount = 0;

  #pragma unroll 1
  for (int t = 0; t < T_LEN; ++t) {
    // ========== S1: alpha; gh0 = Whh0 @ h0n + bhh0 ; attention weights w ==========
    float4 wr1[4][4];
    float bia1[4];
    if (wg < 96) {
      const int rbase = wg * 32 + wv * 4;
      #pragma unroll
      for (int r = 0; r < 4; ++r) {
        const float4* Wp = (const float4*)(Whh0 + (size_t)(rbase + r) * HID);
        #pragma unroll
        for (int p = 0; p < 4; ++p) wr1[r][p] = Wp[p * 64 + lane];
        bia1[r] = bhh0[rbase + r];
      }
    }
    float a0 = ldw(nh0 + tid), a1 = ldw(nh0 + tid + NT);
    float b0 = ldw(nh1 + tid), b1 = ldw(nh1 + tid + NT);
    float uu0 = 0.f, uu1 = 0.f;
    if (wrole && tid < AD) { uu0 = ldw(u0 + tid); uu1 = ldw(u1 + tid); }
    if (wv == 0) {
      float v0 = (lane < 32) ? ldw(e0p + lane) : 0.f;
      float v1 = (lane >= 32 && lane < 48) ? ldw(e1p + lane - 32) : 0.f;
      v0 = wred64(v0); v1 = wred64(v1);
      if (lane == 0) {
        float ea = __expf(v0 + vhb0), eb = __expf(v1 + vhb0);
        float s = ea + eb;
        sal[0] = ea / s; sal[1] = eb / s;
      }
    }
    __syncthreads();
    const float al0 = sal[0], al1 = sal[1];
    xv[tid]      = al0 * a0 + al1 * b0;
    xv[tid + NT] = al0 * a1 + al1 * b1;
    if (wrole && tid < AD) cb[tid] = al0 * uu0 + al1 * uu1;
    __syncthreads();
    if (wg < 96) {
      float4 xw[4];
      #pragma unroll
      for (int p = 0; p < 4; ++p) xw[p] = ((const float4*)xv)[p * 64 + lane];
      const int rbase = wg * 32 + wv * 4;
      float acc[4];
      #pragma unroll
      for (int r = 0; r < 4; ++r) {
        float a = 0.f;
        #pragma unroll
        for (int p = 0; p < 4; ++p) {
          a = fmaf(wr1[r][p].x, xw[p].x, a); a = fmaf(wr1[r][p].y, xw[p].y, a);
          a = fmaf(wr1[r][p].z, xw[p].z, a); a = fmaf(wr1[r][p].w, xw[p].w, a);
        }
        acc[r] = a;
      }
      #pragma unroll
      for (int r = 0; r < 4; ++r) acc[r] = wred64(acc[r]);
      if (lane == 0) {
        #pragma unroll
        for (int r = 0; r < 4; ++r) stw(gh0b + rbase + r, acc[r] + bia1[r]);
      }
    } else {
      const int s0 = (wg - 96) * 16;
      const int sl = wv * 2 + (lane >> 5);
      const int il = lane & 31;
      float acc = 0.f;
      #pragma unroll
      for (int k = 0; k < 8; ++k) {
        const int i = il + k * 32;
        acc = fmaf(vas[i], fast_tanh(exb[sl * AD + i] + cb[i]), acc);
      }
      acc += __shfl_xor(acc, 16, 64); acc += __shfl_xor(acc, 8, 64);
      acc += __shfl_xor(acc, 4, 64);  acc += __shfl_xor(acc, 2, 64); acc += __shfl_xor(acc, 1, 64);
      if (il == 0) stw(wbuf + s0 + sl, __expf(acc + vabv));
    }
    gbar2(bar, wg, ++bcount);

    // ========== S2: nh0 = GRU0((Genc@w)/sum + gi_tok[t], gh0, h0n) ==========
    const int j2 = wg * 8 + wv;
    float4 wr2[3][2];
    #pragma unroll
    for (int r = 0; r < 3; ++r) {
      const float4* Gp = (const float4*)(Genc + (size_t)(r * HID + j2) * S_LEN);
      wr2[r][0] = Gp[lane]; wr2[r][1] = Gp[64 + lane];
    }
    const float* git = gitok + (size_t)t * G3;
    const float git0 = git[j2], git1 = git[HID + j2], git2 = git[2 * HID + j2];
    float gh_r = 0.f, gh_z = 0.f, gh_n = 0.f;
    if (lane == 0) {
      gh_r = ldw(gh0b + j2); gh_z = ldw(gh0b + HID + j2); gh_n = ldw(gh0b + 2 * HID + j2);
    }
    float wv_ = ldw(wbuf + tid);
    wl[tid] = wv_;
    {
      float ps = wred64(wv_);
      if (lane == 0) sred[wv] = ps;
    }
    __syncthreads();
    if (tid == 0) {
      float s = 0.f;
      #pragma unroll
      for (int i = 0; i < 8; ++i) s += sred[i];
      sinv[0] = 1.f / s;
    }
    __syncthreads();
    {
      const float inv = sinv[0];
      float4 xw0 = ((const float4*)wl)[lane], xw1 = ((const float4*)wl)[64 + lane];
      float d[3];
      #pragma unroll
      for (int r = 0; r < 3; ++r) {
        float a = 0.f;
        a = fmaf(wr2[r][0].x, xw0.x, a); a = fmaf(wr2[r][0].y, xw0.y, a);
        a = fmaf(wr2[r][0].z, xw0.z, a); a = fmaf(wr2[r][0].w, xw0.w, a);
        a = fmaf(wr2[r][1].x, xw1.x, a); a = fmaf(wr2[r][1].y, xw1.y, a);
        a = fmaf(wr2[r][1].z, xw1.z, a); a = fmaf(wr2[r][1].w, xw1.w, a);
        d[r] = wred64(a);
      }
      if (lane == 0) {
        const float h0j = xv[j2];
        const float gr = d[0] * inv + git0;
        const float gz = d[1] * inv + git1;
        const float gn = d[2] * inv + git2;
        const float rg = fast_sigmoid(gr + gh_r);
        const float zg = fast_sigmoid(gz + gh_z);
        const float ng = fast_tanh(gn + rg * gh_n);
        stw(nh0 + j2, (1.f - zg) * ng + zg * h0j);
      }
    }
    gbar2(bar, wg, ++bcount);

    // ========== S3: nh1 = GRU1(Wih1@nh0, gh1_prev, nh1_prev); e0, u0 from nh0 ==========
    float4 wr3[6][4];
    float bi3[6], gh3a[2][3], old3[2];
    if (wg < 64) {
      const int j0 = wg * 16 + wv * 2;
      #pragma unroll
      for (int jj = 0; jj < 2; ++jj)
        #pragma unroll
        for (int part = 0; part < 3; ++part) {
          const int r = part * HID + j0 + jj;
          const float4* Wp = (const float4*)(Wih1 + (size_t)r * HID);
          #pragma unroll
          for (int p = 0; p < 4; ++p) wr3[jj * 3 + part][p] = Wp[p * 64 + lane];
          bi3[jj * 3 + part] = bih1[r];
        }
      if (lane == 0) {
        #pragma unroll
        for (int jj = 0; jj < 2; ++jj) {
          gh3a[jj][0] = ldw(gh1b + j0 + jj);
          gh3a[jj][1] = ldw(gh1b + HID + j0 + jj);
          gh3a[jj][2] = ldw(gh1b + 2 * HID + j0 + jj);
          old3[jj]    = ldw(nh1 + j0 + jj);
        }
      }
    } else if (wg < 96) {
      const int r = (wg - 64) * 8 + wv;
      const float4* Wp = (const float4*)(Wh + (size_t)r * HID);
      #pragma unroll
      for (int p = 0; p < 4; ++p) wr3[0][p] = Wp[p * 64 + lane];
      bi3[0] = bh[r]; bi3[1] = vh[r];
    } else {
      const int r = (wg - 96) * 8 + wv;
      const float4* Wp = (const float4*)(Wac + (size_t)r * HID);
      #pragma unroll
      for (int p = 0; p < 4; ++p) wr3[0][p] = Wp[p * 64 + lane];
    }
    {
      float x0 = ldw(nh0 + tid), x1 = ldw(nh0 + tid + NT);
      xv[tid] = x0; xv[tid + NT] = x1;
    }
    __syncthreads();
    {
      float4 xw[4];
      #pragma unroll
      for (int p = 0; p < 4; ++p) xw[p] = ((const float4*)xv)[p * 64 + lane];
      if (wg < 64) {
        const int j0 = wg * 16 + wv * 2;
        float acc[6];
        #pragma unroll
        for (int q = 0; q < 6; ++q) {
          float a = 0.f;
          #pragma unroll
          for (int p = 0; p < 4; ++p) {
            a = fmaf(wr3[q][p].x, xw[p].x, a); a = fmaf(wr3[q][p].y, xw[p].y, a);
            a = fmaf(wr3[q][p].z, xw[p].z, a); a = fmaf(wr3[q][p].w, xw[p].w, a);
          }
          acc[q] = a;
        }
        #pragma unroll
        for (int q = 0; q < 6; ++q) acc[q] = wred64(acc[q]);
        if (lane == 0) {
          #pragma unroll
          for (int jj = 0; jj < 2; ++jj) {
            const float gr = acc[jj * 3 + 0] + bi3[jj * 3 + 0];
            const float gz = acc[jj * 3 + 1] + bi3[jj * 3 + 1];
            const float gn = acc[jj * 3 + 2] + bi3[jj * 3 + 2];
            const float rg = fast_sigmoid(gr + gh3a[jj][0]);
            const float zg = fast_sigmoid(gz + gh3a[jj][1]);
            const float ng = fast_tanh(gn + rg * gh3a[jj][2]);
            const float nv = (1.f - zg) * ng + zg * old3[jj];
            stw(nh1 + j0 + jj, nv);
            H1[(size_t)t * HID + j0 + jj] = nv;
          }
        }
      } else if (wg < 96) {
        float a = 0.f;
        #pragma unroll
        for (int p = 0; p < 4; ++p) {
          a = fmaf(wr3[0][p].x, xw[p].x, a); a = fmaf(wr3[0][p].y, xw[p].y, a);
          a = fmaf(wr3[0][p].z, xw[p].z, a); a = fmaf(wr3[0][p].w, xw[p].w, a);
        }
        a = wred64(a);
        if (lane == 0) sred[wv] = bi3[1] * fast_tanh(a + bi3[0]);
      } else {
        const int r = (wg - 96) * 8 + wv;
        float a = 0.f;
        #pragma unroll
        for (int p = 0; p < 4; ++p) {
          a = fmaf(wr3[0][p].x, xw[p].x, a); a = fmaf(wr3[0][p].y, xw[p].y, a);
          a = fmaf(wr3[0][p].z, xw[p].z, a); a = fmaf(wr3[0][p].w, xw[p].w, a);
        }
        a = wred64(a);
        if (lane == 0) stw(u0 + r, a);
      }
    }
    __syncthreads();
    if (wg >= 64 && wg < 96 && tid == 0) {
      float s = 0.f;
      #pragma unroll
      for (int i = 0; i < 8; ++i) s += sred[i];
      stw(e0p + (wg - 64), s);
    }
    gbar2(bar, wg, ++bcount);

    // ========== S4: gh1_next = Whh1@nh1 + bhh1 ; e1, u1 from nh1 ==========
    float4 wr4[4][4];
    float bi4[4];
    if (wg < 96) {
      const int rbase = wg * 32 + wv * 4;
      #pragma unroll
      for (int r = 0; r < 4; ++r) {
        const float4* Wp = (const float4*)(Whh1 + (size_t)(rbase + r) * HID);
        #pragma unroll
        for (int p = 0; p < 4; ++p) wr4[r][p] = Wp[p * 64 + lane];
        bi4[r] = bhh1[rbase + r];
      }
    } else if (wg < 112) {
      const int rb = (wg - 96) * 16 + wv * 2;
      #pragma unroll
      for (int rr = 0; rr < 2; ++rr) {
        const float4* Wp = (const float4*)(Wh + (size_t)(rb + rr) * HID);
        #pragma unroll
        for (int p = 0; p < 4; ++p) wr4[rr][p] = Wp[p * 64 + lane];
        bi4[rr] = bh[rb + rr]; bi4[2 + rr] = vh[rb + rr];
      }
    } else {
      const int rb = (wg - 112) * 16 + wv * 2;
      #pragma unroll
      for (int rr = 0; rr < 2; ++rr) {
        const float4* Wp = (const float4*)(Wac + (size_t)(rb + rr) * HID);
        #pragma unroll
        for (int p = 0; p < 4; ++p) wr4[rr][p] = Wp[p * 64 + lane];
      }
    }
    {
      float y0 = ldw(nh1 + tid), y1 = ldw(nh1 + tid + NT);
      xv[tid] = y0; xv[tid + NT] = y1;
    }
    __syncthreads();
    {
      float4 xw[4];
      #pragma unroll
      for (int p = 0; p < 4; ++p) xw[p] = ((const float4*)xv)[p * 64 + lane];
      if (wg < 96) {
        const int rbase = wg * 32 + wv * 4;
        float acc[4];
        #pragma unroll
        for (int r = 0; r < 4; ++r) {
          float a = 0.f;
          #pragma unroll
          for (int p = 0; p < 4; ++p) {
            a = fmaf(wr4[r][p].x, xw[p].x, a); a = fmaf(wr4[r][p].y, xw[p].y, a);
            a = fmaf(wr4[r][p].z, xw[p].z, a); a = fmaf(wr4[r][p].w, xw[p].w, a);
          }
          acc[r] = a;
        }
        #pragma unroll
        for (int r = 0; r < 4; ++r) acc[r] = wred64(acc[r]);
        if (lane == 0) {
          #pragma unroll
          for (int r = 0; r < 4; ++r) stw(gh1b + rbase + r, acc[r] + bi4[r]);
        }
      } else if (wg < 112) {
        float acc[2];
        #pragma unroll
        for (int rr = 0; rr < 2; ++rr) {
          float a = 0.f;
          #pragma unroll
          for (int p = 0; p < 4; ++p) {
            a = fmaf(wr4[rr][p].x, xw[p].x, a); a = fmaf(wr4[rr][p].y, xw[p].y, a);
            a = fmaf(wr4[rr][p].z, xw[p].z, a); a = fmaf(wr4[rr][p].w, xw[p].w, a);
          }
          acc[rr] = wred64(a);
        }
        if (lane == 0)
          sred[wv] = bi4[2] * fast_tanh(acc[0] + bi4[0]) + bi4[3] * fast_tanh(acc[1] + bi4[1]);
      } else {
        const int rb = (wg - 112) * 16 + wv * 2;
        float acc[2];
        #pragma unroll
        for (int rr = 0; rr < 2; ++rr) {
          float a = 0.f;
          #pragma unroll
          for (int p = 0; p < 4; ++p) {
            a = fmaf(wr4[rr][p].x, xw[p].x, a); a = fmaf(wr4[rr][p].y, xw[p].y, a);
            a = fmaf(wr4[rr][p].z, xw[p].z, a); a = fmaf(wr4[rr][p].w, xw[p].w, a);
          }
          acc[rr] = wred64(a);
        }
        if (lane == 0) { stw(u1 + rb, acc[0]); stw(u1 + rb + 1, acc[1]); }
      }
    }
    __syncthreads();
    if (wg >= 96 && wg < 112 && tid == 0) {
      float s = 0.f;
      #pragma unroll
      for (int i = 0; i < 8; ++i) s += sred[i];
      stw(e1p + (wg - 96), s);
    }
    gbar2(bar, wg, ++bcount);
  }
}

// ---------------- output head: logits -> exp -> per-wave row partials ----------------
__global__ __launch_bounds__(256) void k_head(
    const float* __restrict__ FC1, const float* __restrict__ Wf2,
    const float* __restrict__ bf2, float* __restrict__ out, float* __restrict__ rowp)
{
  __shared__ float fcb[256 * 32];
  const int v = blockIdx.x * 256 + threadIdx.x;
  const bool ok = v < VOC;
  float wf[32];
  float bb = 0.f;
  if (ok) {
    const float4* W4 = (const float4*)(Wf2 + (size_t)v * 32);
    #pragma unroll
    for (int q = 0; q < 8; ++q) ((float4*)wf)[q] = W4[q];
    bb = bf2[v];
  }
  const int wv = threadIdx.x >> 6;
  #pragma unroll 1
  for (int half = 0; half < 2; ++half) {
    __syncthreads();
    for (int i = threadIdx.x; i < 256 * 32 / 4; i += 256)
      ((float4*)fcb)[i] = ((const float4*)(FC1 + half * 256 * 32))[i];
    __syncthreads();
    #pragma unroll 1
    for (int tt = 0; tt < 256; ++tt) {
      const int t = half * 256 + tt;
      const float4* f4 = (const float4*)(fcb + tt * 32);
      float acc = bb;
      #pragma unroll
      for (int q = 0; q < 8; ++q) {
        float4 f = f4[q];
        acc = fmaf(wf[4*q+0], f.x, acc);
        acc = fmaf(wf[4*q+1], f.y, acc);
        acc = fmaf(wf[4*q+2], f.z, acc);
        acc = fmaf(wf[4*q+3], f.w, acc);
      }
      const float w = ok ? __expf(acc) : 0.f;
      if (ok) out[(size_t)t * VOC + v] = w;
      float r = wred64(w);
      if ((threadIdx.x & 63) == 0)
        rowp[(size_t)t * NPART + (size_t)blockIdx.x * 4 + wv] = r;
    }
  }
}

__global__ __launch_bounds__(256) void k_rowsum(const float* __restrict__ rowp, float* __restrict__ inv) {
  const int t = blockIdx.x;
  float acc = 0.f;
  for (int i = threadIdx.x; i < NPART; i += 256) acc += rowp[(size_t)t * NPART + i];
  acc = wred64(acc);
  __shared__ float sr[4];
  if ((threadIdx.x & 63) == 0) sr[threadIdx.x >> 6] = acc;
  __syncthreads();
  if (threadIdx.x == 0) inv[t] = 1.f / (sr[0] + sr[1] + sr[2] + sr[3]);
}

__global__ __launch_bounds__(256) void k_scale(float* __restrict__ out, const float* __restrict__ inv) {
  const int t = blockIdx.y;
  const float s = inv[t];
  const size_t base = (size_t)t * VOC;
  const int v0 = blockIdx.x * 2048 + threadIdx.x;
  #pragma unroll
  for (int k = 0; k < 8; ++k) {
    const int v = v0 + k * 256;
    if (v < VOC) out[base + v] *= s;
  }
}

extern "C" void kernel_launch(void* const* d_in, const int* in_sizes, int n_in,
                              void* d_out, int out_size, void* d_ws, size_t ws_size,
                              hipStream_t stream) {
  const int*   dec  = (const int*)  d_in[0];
  const float* enc  = (const float*)d_in[1];
  const float* emb  = (const float*)d_in[2];
  const float* Wax  = (const float*)d_in[3];
  const float* Wac  = (const float*)d_in[4];
  const float* ba   = (const float*)d_in[5];
  const float* va   = (const float*)d_in[6];
  const float* vab  = (const float*)d_in[7];
  const float* Wih0 = (const float*)d_in[8];
  const float* bih0 = (const float*)d_in[9];
  const float* Whh0 = (const float*)d_in[10];
  const float* bhh0 = (const float*)d_in[11];
  const float* Wih1 = (const float*)d_in[12];
  const float* bih1 = (const float*)d_in[13];
  const float* Whh1 = (const float*)d_in[14];
  const float* bhh1 = (const float*)d_in[15];
  const float* Wh   = (const float*)d_in[16];
  const float* bh   = (const float*)d_in[17];
  const float* vh   = (const float*)d_in[18];
  const float* vhb  = (const float*)d_in[19];
  const float* Wf1  = (const float*)d_in[20];
  const float* bf1  = (const float*)d_in[21];
  const float* Wf2  = (const float*)d_in[22];
  const float* bf2  = (const float*)d_in[23];
  float* out = (float*)d_out;
  float* ws  = (float*)d_ws;

  k_init<<<1, 256, 0, stream>>>(ws, bhh1);

  // Genc[r][s] = Wih0[r, :1024] . enc[s]          (M=3072, N=512)
  k_gemm<<<dim3(8, 48), 256, 0, stream>>>(Wih0, 2048, nullptr, enc, 1024, 0,
                                          nullptr, ws + WS_GENC, 512, G3, S_LEN, 0);
  // gi_tok[t][r] = emb[dec[t]] . Wih0[r, 1024:] + bih0[r]   (M=512, N=3072)
  k_gemm<<<dim3(48, 8), 256, 0, stream>>>(emb, 1024, dec, Wih0, 2048, 1024,
                                          bih0, ws + WS_GITOK, G3, T_LEN, G3, 0);
  // Ex[s][i] = enc[s] . Wa_x[i] + ba[i]           (M=512, N=256)
  k_gemm<<<dim3(4, 8), 256, 0, stream>>>(enc, 1024, nullptr, Wax, 1024, 0,
                                         ba, ws + WS_EX, AD, S_LEN, AD, 0);

  k_recur<<<NWG, NT, 0, stream>>>(ws, Whh0, bhh0, Wih1, bih1, Whh1, bhh1,
                                  Wh, bh, vh, vhb, va, vab, Wac);

  // FC1[t] = relu(Wf1 @ H1[t] + bf1)              (M=512, N=32)
  k_gemm<<<dim3(1, 8), 256, 0, stream>>>(ws + WS_H1, 1024, nullptr, Wf1, 1024, 0,
                                         bf1, ws + WS_FC1, 32, T_LEN, 32, 1);

  k_head<<<197, 256, 0, stream>>>(ws + WS_FC1, Wf2, bf2, out, ws + WS_ROWP);
  k_rowsum<<<512, 256, 0, stream>>>(ws + WS_ROWP, ws + WS_INV);
  k_scale<<<dim3(25, 512), 256, 0, stream>>>(out, ws + WS_INV);
}

// Round 3
// 5518.164 us; speedup vs baseline: 5.3084x; 2.6928x over previous
//
#include <hip/hip_runtime.h>
#include <cstdint>
#include <cstddef>

#define T_LEN 512
#define S_LEN 512
#define HID   1024
#define AD    256
#define VOC   50257
#define G3    3072
#define NWG   256
#define NT    512
#define NPART (197*4)

// ---------------- workspace layout (float offsets) ----------------
#define WS_GENC   0
#define WS_GITOK  (WS_GENC + G3*S_LEN)          // [512][3072]
#define WS_EX     (WS_GITOK + T_LEN*G3)         // [512][256]
#define WS_H1     (WS_EX + S_LEN*AD)            // [512][1024]
#define WS_FC1    (WS_H1 + T_LEN*HID)           // [512][32]
#define WS_NH0    (WS_FC1 + T_LEN*32)
#define WS_NH1    (WS_NH0 + HID)
#define WS_WB     (WS_NH1 + HID)                 // 512
#define WS_U0     (WS_WB + S_LEN)                // 256
#define WS_U1     (WS_U0 + AD)                   // 256
#define WS_E0P    (WS_U1 + AD)                   // 256
#define WS_E1P    (WS_E0P + 256)                 // 256
#define WS_BARX   (WS_E1P + 256)                 // 384 uints (256 slots + gen)
#define WS_ROWP   (WS_BARX + 384)                // [512][788]
#define WS_INV    (WS_ROWP + T_LEN*NPART)
#define WS_END    (WS_INV + T_LEN)

__device__ inline float wred64(float v) {
  v += __shfl_xor(v, 32, 64); v += __shfl_xor(v, 16, 64); v += __shfl_xor(v, 8, 64);
  v += __shfl_xor(v, 4, 64);  v += __shfl_xor(v, 2, 64);  v += __shfl_xor(v, 1, 64);
  return v;
}

__device__ inline float fast_sigmoid(float x) { return 1.f / (1.f + __expf(-x)); }
__device__ inline float fast_tanh(float x) {
  float e = __expf(2.f * x);
  return 1.f - 2.f / (e + 1.f);
}

// agent-scope (L2-coherent, L1-bypassing) state accessors
__device__ inline float ldw(const float* p) {
  return __uint_as_float(__hip_atomic_load((const unsigned int*)p,
                                           __ATOMIC_RELAXED, __HIP_MEMORY_SCOPE_AGENT));
}
__device__ inline void stw(float* p, float v) {
  __hip_atomic_store((unsigned int*)p, __float_as_uint(v),
                     __ATOMIC_RELAXED, __HIP_MEMORY_SCOPE_AGENT);
}
__device__ inline unsigned ldu(const unsigned* p) {
  return __hip_atomic_load(p, __ATOMIC_RELAXED, __HIP_MEMORY_SCOPE_AGENT);
}
__device__ inline void stu(unsigned* p, unsigned v) {
  __hip_atomic_store(p, v, __ATOMIC_RELAXED, __HIP_MEMORY_SCOPE_AGENT);
}

// checker-style grid barrier: contention-free arrivals (slot per WG),
// WG0's first 256 threads poll all slots in parallel, then publish gen.
// __syncthreads before arrival drains vmcnt -> all prior stw visible at L2.
__device__ inline void gbar(unsigned* slot, unsigned* gen, unsigned b) {
  __syncthreads();
  if (threadIdx.x == 0) stu(slot + blockIdx.x, b);
  if (blockIdx.x == 0) {
    if (threadIdx.x < NWG) {
      while (ldu(slot + threadIdx.x) < b) __builtin_amdgcn_s_sleep(1);
    }
    __syncthreads();
    if (threadIdx.x == 0) stu(gen, b);
  } else {
    if (threadIdx.x == 0) {
      while (ldu(gen) < b) __builtin_amdgcn_s_sleep(1);
    }
    __syncthreads();
  }
}

__device__ inline float qdot4(const float4& a0, const float4& a1, const float4& a2, const float4& a3,
                              const float4& x0, const float4& x1, const float4& x2, const float4& x3) {
  float a = 0.f;
  a = fmaf(a0.x, x0.x, a); a = fmaf(a0.y, x0.y, a); a = fmaf(a0.z, x0.z, a); a = fmaf(a0.w, x0.w, a);
  a = fmaf(a1.x, x1.x, a); a = fmaf(a1.y, x1.y, a); a = fmaf(a1.z, x1.z, a); a = fmaf(a1.w, x1.w, a);
  a = fmaf(a2.x, x2.x, a); a = fmaf(a2.y, x2.y, a); a = fmaf(a2.z, x2.z, a); a = fmaf(a2.w, x2.w, a);
  a = fmaf(a3.x, x3.x, a); a = fmaf(a3.y, x3.y, a); a = fmaf(a3.z, x3.z, a); a = fmaf(a3.w, x3.w, a);
  return a;
}
__device__ inline float qdot2(const float4& a0, const float4& a1,
                              const float4& x0, const float4& x1) {
  float a = 0.f;
  a = fmaf(a0.x, x0.x, a); a = fmaf(a0.y, x0.y, a); a = fmaf(a0.z, x0.z, a); a = fmaf(a0.w, x0.w, a);
  a = fmaf(a1.x, x1.x, a); a = fmaf(a1.y, x1.y, a); a = fmaf(a1.z, x1.z, a); a = fmaf(a1.w, x1.w, a);
  return a;
}

// ---------------- init: zero recurrent state + barrier ----------------
__global__ void k_init(float* ws) {
  const int tid = threadIdx.x;
  for (int i = tid; i < HID; i += 256) { ws[WS_NH0 + i] = 0.f; ws[WS_NH1 + i] = 0.f; }
  if (tid < AD) { ws[WS_U0 + tid] = 0.f; ws[WS_U1 + tid] = 0.f; }
  ws[WS_E0P + tid] = 0.f;   // 256
  ws[WS_E1P + tid] = 0.f;   // 256
  for (int i = tid; i < 384; i += 256) ((unsigned*)(ws + WS_BARX))[i] = 0u;
}

// ---------------- generic tiled fp32 GEMM (pre/post passes) ----------------
__global__ __launch_bounds__(256) void k_gemm(
    const float* __restrict__ A, int lda, const int* __restrict__ gidx,
    const float* __restrict__ B, int ldb, int kofs,
    const float* __restrict__ bias, float* __restrict__ C, int ldc,
    int M, int N, int act)
{
  __shared__ float As[64][33];
  __shared__ float Bs[64][33];
  const int bm = blockIdx.y * 64, bn = blockIdx.x * 64;
  const int tx = threadIdx.x & 15, ty = threadIdx.x >> 4;
  float acc[4][4] = {};
  const int lin = threadIdx.x * 8;
  const int lr = lin >> 5;
  const int lc = lin & 31;
  for (int k0 = 0; k0 < 1024; k0 += 32) {
    {
      const int gm = bm + lr;
      float4 v0 = {0,0,0,0}, v1 = {0,0,0,0};
      if (gm < M) {
        const int row = gidx ? gidx[gm] : gm;
        const float* p = A + (size_t)row * lda + k0 + lc;
        v0 = *(const float4*)p; v1 = *(const float4*)(p + 4);
      }
      As[lr][lc+0]=v0.x; As[lr][lc+1]=v0.y; As[lr][lc+2]=v0.z; As[lr][lc+3]=v0.w;
      As[lr][lc+4]=v1.x; As[lr][lc+5]=v1.y; As[lr][lc+6]=v1.z; As[lr][lc+7]=v1.w;
    }
    {
      const int gn = bn + lr;
      float4 v0 = {0,0,0,0}, v1 = {0,0,0,0};
      if (gn < N) {
        const float* p = B + (size_t)gn * ldb + kofs + k0 + lc;
        v0 = *(const float4*)p; v1 = *(const float4*)(p + 4);
      }
      Bs[lr][lc+0]=v0.x; Bs[lr][lc+1]=v0.y; Bs[lr][lc+2]=v0.z; Bs[lr][lc+3]=v0.w;
      Bs[lr][lc+4]=v1.x; Bs[lr][lc+5]=v1.y; Bs[lr][lc+6]=v1.z; Bs[lr][lc+7]=v1.w;
    }
    __syncthreads();
    #pragma unroll
    for (int kk = 0; kk < 32; ++kk) {
      float a0 = As[ty*4+0][kk], a1 = As[ty*4+1][kk], a2 = As[ty*4+2][kk], a3 = As[ty*4+3][kk];
      float b0 = Bs[tx*4+0][kk], b1 = Bs[tx*4+1][kk], b2 = Bs[tx*4+2][kk], b3 = Bs[tx*4+3][kk];
      acc[0][0]=fmaf(a0,b0,acc[0][0]); acc[0][1]=fmaf(a0,b1,acc[0][1]); acc[0][2]=fmaf(a0,b2,acc[0][2]); acc[0][3]=fmaf(a0,b3,acc[0][3]);
      acc[1][0]=fmaf(a1,b0,acc[1][0]); acc[1][1]=fmaf(a1,b1,acc[1][1]); acc[1][2]=fmaf(a1,b2,acc[1][2]); acc[1][3]=fmaf(a1,b3,acc[1][3]);
      acc[2][0]=fmaf(a2,b0,acc[2][0]); acc[2][1]=fmaf(a2,b1,acc[2][1]); acc[2][2]=fmaf(a2,b2,acc[2][2]); acc[2][3]=fmaf(a2,b3,acc[2][3]);
      acc[3][0]=fmaf(a3,b0,acc[3][0]); acc[3][1]=fmaf(a3,b1,acc[3][1]); acc[3][2]=fmaf(a3,b2,acc[3][2]); acc[3][3]=fmaf(a3,b3,acc[3][3]);
    }
    __syncthreads();
  }
  #pragma unroll
  for (int i = 0; i < 4; ++i)
    #pragma unroll
    for (int j = 0; j < 4; ++j) {
      const int m = bm + ty*4 + i, n = bn + tx*4 + j;
      if (m < M && n < N) {
        float v = acc[i][j] + (bias ? bias[n] : 0.f);
        if (act == 1) v = fmaxf(v, 0.f);
        C[(size_t)m * ldc + n] = v;
      }
    }
}

// ---------------- persistent recurrence: 256 WGs x 512 thr, register-resident weights ----------------
// WG wg owns j-columns [4wg, 4wg+4) -> 12 gate-rows {part*1024 + j} of Whh0/Wih1/Whh1/Genc.
// waves 0..5: 2 gate-rows each (lr = 2*wv+r, lr = part*4 + jl). wave 6: Wh row wg (e0/e1).
// wave 7: Wac row wg (u0/u1). waves 6,7 also: attention-w rows s = 2wg+(wv-6).
__global__ __launch_bounds__(NT) void k_recur(
    float* __restrict__ ws,
    const float* __restrict__ Whh0, const float* __restrict__ bhh0,
    const float* __restrict__ Wih1, const float* __restrict__ bih1,
    const float* __restrict__ Whh1, const float* __restrict__ bhh1,
    const float* __restrict__ Wh,   const float* __restrict__ bh,
    const float* __restrict__ vh,   const float* __restrict__ vhb,
    const float* __restrict__ va,   const float* __restrict__ vab,
    const float* __restrict__ Wac)
{
  const float* Genc  = ws + WS_GENC;
  const float* gitok = ws + WS_GITOK;
  const float* Ex    = ws + WS_EX;
  float* H1    = ws + WS_H1;
  float* nh0g  = ws + WS_NH0;
  float* nh1g  = ws + WS_NH1;
  float* wbufg = ws + WS_WB;
  float* u0g   = ws + WS_U0;
  float* u1g   = ws + WS_U1;
  float* e0pg  = ws + WS_E0P;
  float* e1pg  = ws + WS_E1P;
  unsigned* slot = (unsigned*)(ws + WS_BARX);
  unsigned* gen  = slot + NWG;

  const int wg = blockIdx.x, tid = threadIdx.x;
  const int lane = tid & 63, wv = tid >> 6;

  __shared__ float xv[HID];      // staged state vector (h0n / nh0 / nh1)
  __shared__ float wl[S_LEN];    // staged attention weights
  __shared__ float cb[AD];       // c = Wa_c @ h0n
  __shared__ float sgit[12], sgh0[12], gh1l[12], sb0[12], sbh1[12], sacc[12];
  __shared__ float sred[8], sal[2], ssc[1];

  // ---- persistent register-resident weights ----
  float4 wreg[28];
  if (wv < 6) {
    #pragma unroll
    for (int r = 0; r < 2; ++r) {
      const int lr = 2 * wv + r;
      const int g = (lr >> 2) * HID + wg * 4 + (lr & 3);
      const float4* p0 = (const float4*)(Whh0 + (size_t)g * HID);
      const float4* p1 = (const float4*)(Wih1 + (size_t)g * HID);
      const float4* p2 = (const float4*)(Whh1 + (size_t)g * HID);
      const float4* pg = (const float4*)(Genc + (size_t)g * S_LEN);
      #pragma unroll
      for (int p = 0; p < 4; ++p) {
        wreg[r*4+p]      = p0[p*64 + lane];
        wreg[8 + r*4+p]  = p1[p*64 + lane];
        wreg[16 + r*4+p] = p2[p*64 + lane];
      }
      #pragma unroll
      for (int p = 0; p < 2; ++p) wreg[24 + r*2+p] = pg[p*64 + lane];
    }
  } else {
    const float* Wrow = (wv == 6) ? (Wh + (size_t)wg * HID) : (Wac + (size_t)wg * HID);
    const float4* p0 = (const float4*)Wrow;
    #pragma unroll
    for (int p = 0; p < 4; ++p) wreg[p] = p0[p*64 + lane];
    const int s = 2 * wg + (wv - 6);
    wreg[4] = ((const float4*)(Ex + (size_t)s * AD))[lane];
    wreg[5] = ((const float4*)va)[lane];
  }

  // combiner biases (threads 0..3, jl = tid)
  float i1r = 0.f, i1z = 0.f, i1n = 0.f;
  if (tid < 4) {
    const int j = wg * 4 + tid;
    i1r = bih1[j]; i1z = bih1[HID + j]; i1n = bih1[2 * HID + j];
  }
  if (tid < 12) {
    const int g = (tid >> 2) * HID + wg * 4 + (tid & 3);
    sb0[tid] = bhh0[g];
    const float bb = bhh1[g];
    sbh1[tid] = bb;
    gh1l[tid] = bb;          // gh1(t=0) = Whh1@0 + bhh1
  }
  const float vhW = vh[wg], bhW = bh[wg];
  const float vabv = vab[0], vhb0 = vhb[0];
  unsigned b = 0;
  __syncthreads();

  const float4* XV4 = (const float4*)xv;
  const float4* WL4 = (const float4*)wl;
  const float4* CB4 = (const float4*)cb;

  #pragma unroll 1
  for (int t = 0; t < T_LEN; ++t) {
    // ========== S1: alpha; h0n; c; gh0 = Whh0@h0n + bhh0 ; attention w ==========
    {
      // issue all cross-WG state loads up front
      const float a0 = ldw(nh0g + tid), a1 = ldw(nh0g + 512 + tid);
      const float b0 = ldw(nh1g + tid), b1 = ldw(nh1g + 512 + tid);
      float uu0 = 0.f, uu1 = 0.f;
      if (tid < AD) { uu0 = ldw(u0g + tid); uu1 = ldw(u1g + tid); }
      float ep = (tid < 256) ? ldw(e0pg + tid) : ldw(e1pg + tid - 256);
      if (tid < 12)
        sgit[tid] = gitok[(size_t)t * G3 + (tid >> 2) * HID + wg * 4 + (tid & 3)];
      ep = wred64(ep);
      if (lane == 0) sred[wv] = ep;
      __syncthreads();
      if (tid == 0) {
        const float e0 = sred[0] + sred[1] + sred[2] + sred[3] + vhb0;
        const float e1 = sred[4] + sred[5] + sred[6] + sred[7] + vhb0;
        const float ea = __expf(e0), eb = __expf(e1);
        const float s = ea + eb;
        sal[0] = ea / s; sal[1] = eb / s;
      }
      __syncthreads();
      const float al0 = sal[0], al1 = sal[1];
      xv[tid]       = al0 * a0 + al1 * b0;
      xv[tid + 512] = al0 * a1 + al1 * b1;
      if (tid < AD) cb[tid] = al0 * uu0 + al1 * uu1;
      __syncthreads();
      if (wv < 6) {
        const float4 x0 = XV4[lane], x1 = XV4[64+lane], x2 = XV4[128+lane], x3 = XV4[192+lane];
        float accA = qdot4(wreg[0], wreg[1], wreg[2], wreg[3], x0, x1, x2, x3);
        float accB = qdot4(wreg[4], wreg[5], wreg[6], wreg[7], x0, x1, x2, x3);
        accA = wred64(accA); accB = wred64(accB);
        if (lane == 0) {
          sgh0[2*wv]     = accA + sb0[2*wv];
          sgh0[2*wv + 1] = accB + sb0[2*wv + 1];
        }
      } else {
        const float4 e4 = wreg[4], v4 = wreg[5], c4 = CB4[lane];
        const float s0 = fast_tanh(e4.x + c4.x);
        const float s1 = fast_tanh(e4.y + c4.y);
        const float s2 = fast_tanh(e4.z + c4.z);
        const float s3 = fast_tanh(e4.w + c4.w);
        float acc = v4.x*s0 + v4.y*s1 + v4.z*s2 + v4.w*s3;
        acc = wred64(acc);
        if (lane == 0) stw(wbufg + 2*wg + (wv - 6), __expf(acc + vabv));
      }
    }
    gbar(slot, gen, ++b);

    // ========== S2: nh0 = GRU0((Genc@w)/sum + gi_tok, gh0, h0n) ==========
    {
      const float wval = ldw(wbufg + tid);
      wl[tid] = wval;
      const float ps = wred64(wval);
      if (lane == 0) sred[wv] = ps;
      __syncthreads();
      if (tid == 0) {
        float s = 0.f;
        #pragma unroll
        for (int i = 0; i < 8; ++i) s += sred[i];
        ssc[0] = 1.f / s;
      }
      if (wv < 6) {
        const float4 w0 = WL4[lane], w1 = WL4[64 + lane];
        float accA = qdot2(wreg[24], wreg[25], w0, w1);
        float accB = qdot2(wreg[26], wreg[27], w0, w1);
        accA = wred64(accA); accB = wred64(accB);
        if (lane == 0) { sacc[2*wv] = accA; sacc[2*wv + 1] = accB; }
      }
      __syncthreads();
      if (tid < 4) {
        const float inv = ssc[0];
        const float d0 = sacc[tid]     * inv + sgit[tid];
        const float d1 = sacc[4 + tid] * inv + sgit[4 + tid];
        const float d2 = sacc[8 + tid] * inv + sgit[8 + tid];
        const float rg = fast_sigmoid(d0 + sgh0[tid]);
        const float zg = fast_sigmoid(d1 + sgh0[4 + tid]);
        const float ng = fast_tanh(d2 + rg * sgh0[8 + tid]);
        const float h0j = xv[wg * 4 + tid];
        stw(nh0g + wg * 4 + tid, (1.f - zg) * ng + zg * h0j);
      }
    }
    gbar(slot, gen, ++b);

    // ========== S3: nh1 = GRU1(Wih1@nh0, gh1_prev, nh1_prev); e0, u0 ==========
    {
      const float x0 = ldw(nh0g + tid), x1 = ldw(nh0g + 512 + tid);
      const float oldn = (tid < 4) ? ldw(nh1g + wg * 4 + tid) : 0.f;
      xv[tid] = x0; xv[tid + 512] = x1;
      __syncthreads();
      const float4 y0 = XV4[lane], y1 = XV4[64+lane], y2 = XV4[128+lane], y3 = XV4[192+lane];
      if (wv < 6) {
        float accA = qdot4(wreg[8],  wreg[9],  wreg[10], wreg[11], y0, y1, y2, y3);
        float accB = qdot4(wreg[12], wreg[13], wreg[14], wreg[15], y0, y1, y2, y3);
        accA = wred64(accA); accB = wred64(accB);
        if (lane == 0) { sacc[2*wv] = accA; sacc[2*wv + 1] = accB; }
      } else {
        float acc = qdot4(wreg[0], wreg[1], wreg[2], wreg[3], y0, y1, y2, y3);
        acc = wred64(acc);
        if (lane == 0) {
          if (wv == 6) stw(e0pg + wg, vhW * fast_tanh(acc + bhW));
          else         stw(u0g + wg, acc);
        }
      }
      __syncthreads();
      if (tid < 4) {
        const float gr = sacc[tid]     + i1r;
        const float gz = sacc[4 + tid] + i1z;
        const float gn = sacc[8 + tid] + i1n;
        const float rg = fast_sigmoid(gr + gh1l[tid]);
        const float zg = fast_sigmoid(gz + gh1l[4 + tid]);
        const float ng = fast_tanh(gn + rg * gh1l[8 + tid]);
        const float nv = (1.f - zg) * ng + zg * oldn;
        stw(nh1g + wg * 4 + tid, nv);
        H1[(size_t)t * HID + wg * 4 + tid] = nv;
      }
    }
    gbar(slot, gen, ++b);

    // ========== S4: gh1_next = Whh1@nh1 + bhh1 ; e1, u1 ==========
    {
      const float x0 = ldw(nh1g + tid), x1 = ldw(nh1g + 512 + tid);
      xv[tid] = x0; xv[tid + 512] = x1;
      __syncthreads();
      const float4 y0 = XV4[lane], y1 = XV4[64+lane], y2 = XV4[128+lane], y3 = XV4[192+lane];
      if (wv < 6) {
        float accA = qdot4(wreg[16], wreg[17], wreg[18], wreg[19], y0, y1, y2, y3);
        float accB = qdot4(wreg[20], wreg[21], wreg[22], wreg[23], y0, y1, y2, y3);
        accA = wred64(accA); accB = wred64(accB);
        if (lane == 0) {
          gh1l[2*wv]     = accA + sbh1[2*wv];
          gh1l[2*wv + 1] = accB + sbh1[2*wv + 1];
        }
      } else {
        float acc = qdot4(wreg[0], wreg[1], wreg[2], wreg[3], y0, y1, y2, y3);
        acc = wred64(acc);
        if (lane == 0) {
          if (wv == 6) stw(e1pg + wg, vhW * fast_tanh(acc + bhW));
          else         stw(u1g + wg, acc);
        }
      }
    }
    gbar(slot, gen, ++b);
  }
}

// ---------------- output head: logits -> exp -> per-wave row partials ----------------
__global__ __launch_bounds__(256) void k_head(
    const float* __restrict__ FC1, const float* __restrict__ Wf2,
    const float* __restrict__ bf2, float* __restrict__ out, float* __restrict__ rowp)
{
  __shared__ float fcb[256 * 32];
  const int v = blockIdx.x * 256 + threadIdx.x;
  const bool ok = v < VOC;
  float wf[32];
  float bb = 0.f;
  if (ok) {
    const float4* W4 = (const float4*)(Wf2 + (size_t)v * 32);
    #pragma unroll
    for (int q = 0; q < 8; ++q) ((float4*)wf)[q] = W4[q];
    bb = bf2[v];
  }
  const int wv = threadIdx.x >> 6;
  #pragma unroll 1
  for (int half = 0; half < 2; ++half) {
    __syncthreads();
    for (int i = threadIdx.x; i < 256 * 32 / 4; i += 256)
      ((float4*)fcb)[i] = ((const float4*)(FC1 + half * 256 * 32))[i];
    __syncthreads();
    #pragma unroll 1
    for (int tt = 0; tt < 256; ++tt) {
      const int t = half * 256 + tt;
      const float4* f4 = (const float4*)(fcb + tt * 32);
      float acc = bb;
      #pragma unroll
      for (int q = 0; q < 8; ++q) {
        float4 f = f4[q];
        acc = fmaf(wf[4*q+0], f.x, acc);
        acc = fmaf(wf[4*q+1], f.y, acc);
        acc = fmaf(wf[4*q+2], f.z, acc);
        acc = fmaf(wf[4*q+3], f.w, acc);
      }
      const float w = ok ? __expf(acc) : 0.f;
      if (ok) out[(size_t)t * VOC + v] = w;
      float r = wred64(w);
      if ((threadIdx.x & 63) == 0)
        rowp[(size_t)t * NPART + (size_t)blockIdx.x * 4 + wv] = r;
    }
  }
}

__global__ __launch_bounds__(256) void k_rowsum(const float* __restrict__ rowp, float* __restrict__ inv) {
  const int t = blockIdx.x;
  float acc = 0.f;
  for (int i = threadIdx.x; i < NPART; i += 256) acc += rowp[(size_t)t * NPART + i];
  acc = wred64(acc);
  __shared__ float sr[4];
  if ((threadIdx.x & 63) == 0) sr[threadIdx.x >> 6] = acc;
  __syncthreads();
  if (threadIdx.x == 0) inv[t] = 1.f / (sr[0] + sr[1] + sr[2] + sr[3]);
}

__global__ __launch_bounds__(256) void k_scale(float* __restrict__ out, const float* __restrict__ inv) {
  const int t = blockIdx.y;
  const float s = inv[t];
  const size_t base = (size_t)t * VOC;
  const int v0 = blockIdx.x * 2048 + threadIdx.x;
  #pragma unroll
  for (int k = 0; k < 8; ++k) {
    const int v = v0 + k * 256;
    if (v < VOC) out[base + v] *= s;
  }
}

extern "C" void kernel_launch(void* const* d_in, const int* in_sizes, int n_in,
                              void* d_out, int out_size, void* d_ws, size_t ws_size,
                              hipStream_t stream) {
  const int*   dec  = (const int*)  d_in[0];
  const float* enc  = (const float*)d_in[1];
  const float* emb  = (const float*)d_in[2];
  const float* Wax  = (const float*)d_in[3];
  const float* Wac  = (const float*)d_in[4];
  const float* ba   = (const float*)d_in[5];
  const float* va   = (const float*)d_in[6];
  const float* vab  = (const float*)d_in[7];
  const float* Wih0 = (const float*)d_in[8];
  const float* bih0 = (const float*)d_in[9];
  const float* Whh0 = (const float*)d_in[10];
  const float* bhh0 = (const float*)d_in[11];
  const float* Wih1 = (const float*)d_in[12];
  const float* bih1 = (const float*)d_in[13];
  const float* Whh1 = (const float*)d_in[14];
  const float* bhh1 = (const float*)d_in[15];
  const float* Wh   = (const float*)d_in[16];
  const float* bh   = (const float*)d_in[17];
  const float* vh   = (const float*)d_in[18];
  const float* vhb  = (const float*)d_in[19];
  const float* Wf1  = (const float*)d_in[20];
  const float* bf1  = (const float*)d_in[21];
  const float* Wf2  = (const float*)d_in[22];
  const float* bf2  = (const float*)d_in[23];
  float* out = (float*)d_out;
  float* ws  = (float*)d_ws;

  k_init<<<1, 256, 0, stream>>>(ws);

  // Genc[r][s] = Wih0[r, :1024] . enc[s]          (M=3072, N=512)
  k_gemm<<<dim3(8, 48), 256, 0, stream>>>(Wih0, 2048, nullptr, enc, 1024, 0,
                                          nullptr, ws + WS_GENC, 512, G3, S_LEN, 0);
  // gi_tok[t][r] = emb[dec[t]] . Wih0[r, 1024:] + bih0[r]   (M=512, N=3072)
  k_gemm<<<dim3(48, 8), 256, 0, stream>>>(emb, 1024, dec, Wih0, 2048, 1024,
                                          bih0, ws + WS_GITOK, G3, T_LEN, G3, 0);
  // Ex[s][i] = enc[s] . Wa_x[i] + ba[i]           (M=512, N=256)
  k_gemm<<<dim3(4, 8), 256, 0, stream>>>(enc, 1024, nullptr, Wax, 1024, 0,
                                         ba, ws + WS_EX, AD, S_LEN, AD, 0);

  k_recur<<<NWG, NT, 0, stream>>>(ws, Whh0, bhh0, Wih1, bih1, Whh1, bhh1,
                                  Wh, bh, vh, vhb, va, vab, Wac);

  // FC1[t] = relu(Wf1 @ H1[t] + bf1)              (M=512, N=32)
  k_gemm<<<dim3(1, 8), 256, 0, stream>>>(ws + WS_H1, 1024, nullptr, Wf1, 1024, 0,
                                         bf1, ws + WS_FC1, 32, T_LEN, 32, 1);

  k_head<<<197, 256, 0, stream>>>(ws + WS_FC1, Wf2, bf2, out, ws + WS_ROWP);
  k_rowsum<<<512, 256, 0, stream>>>(ws + WS_ROWP, ws + WS_INV);
  k_scale<<<dim3(25, 512), 256, 0, stream>>>(out, ws + WS_INV);
}